// Round 3
// baseline (112.767 us; speedup 1.0000x reference)
//
#include <hip/hip_runtime.h>

// Sobel gradient magnitude on [B=32, 1, H=1024, W=1024] f32, zero ("SAME") padding.
// Separable: Gx = vsmooth[1,2,1] then hdiff[-1,0,1]; Gy = vdiff[-1,0,1] then hsmooth[1,2,1].
// Each thread produces 4 contiguous outputs (one float4).

constexpr int W = 1024;
constexpr int H = 1024;
constexpr int B = 32;
constexpr int G = W / 4;  // float4 groups per row = 256

__global__ __launch_bounds__(256) void sobel_kernel(const float* __restrict__ x,
                                                    float* __restrict__ out) {
    const int idx = blockIdx.x * blockDim.x + threadIdx.x;
    // idx -> (b, r, g): G=256, H=1024 are powers of two
    const int g = idx & (G - 1);
    const int r = (idx >> 8) & (H - 1);
    const int b = idx >> 18;

    const size_t img_off = (size_t)b * H * W;
    const float* __restrict__ img = x + img_off;
    const int c0 = g << 2;

    const bool has_up   = (r > 0);
    const bool has_dn   = (r < H - 1);
    const bool has_l    = (c0 > 0);
    const bool has_r    = (c0 + 4 < W);

    const float* rowm = img + (size_t)(r - 1) * W;
    const float* row0 = img + (size_t)r * W;
    const float* rowp = img + (size_t)(r + 1) * W;

    const float4 zero4 = make_float4(0.f, 0.f, 0.f, 0.f);
    // Aligned 16B loads for the 3-row window (coalesced: lane i -> base + i*16)
    const float4 a = has_up ? *reinterpret_cast<const float4*>(rowm + c0) : zero4;
    const float4 m = *reinterpret_cast<const float4*>(row0 + c0);
    const float4 p = has_dn ? *reinterpret_cast<const float4*>(rowp + c0) : zero4;

    // Edge scalars (L1 hits: same cache lines as neighbor lanes' float4 loads)
    const float la = (has_l && has_up) ? rowm[c0 - 1] : 0.f;
    const float lm = has_l ? row0[c0 - 1] : 0.f;
    const float lp = (has_l && has_dn) ? rowp[c0 - 1] : 0.f;
    const float ra = (has_r && has_up) ? rowm[c0 + 4] : 0.f;
    const float rm = has_r ? row0[c0 + 4] : 0.f;
    const float rp = (has_r && has_dn) ? rowp[c0 + 4] : 0.f;

    // Vertical smooth t = up + 2*mid + dn, vertical diff d = dn - up, per column
    const float tL = la + 2.f * lm + lp;
    const float t0 = a.x + 2.f * m.x + p.x;
    const float t1 = a.y + 2.f * m.y + p.y;
    const float t2 = a.z + 2.f * m.z + p.z;
    const float t3 = a.w + 2.f * m.w + p.w;
    const float tR = ra + 2.f * rm + rp;

    const float dL = lp - la;
    const float d0 = p.x - a.x;
    const float d1 = p.y - a.y;
    const float d2 = p.z - a.z;
    const float d3 = p.w - a.w;
    const float dR = rp - ra;

    // Horizontal combine: gx[j] = t[j+1] - t[j-1]; gy[j] = d[j-1] + 2*d[j] + d[j+1]
    const float gx0 = t1 - tL;
    const float gx1 = t2 - t0;
    const float gx2 = t3 - t1;
    const float gx3 = tR - t2;

    const float gy0 = dL + 2.f * d0 + d1;
    const float gy1 = d0 + 2.f * d1 + d2;
    const float gy2 = d1 + 2.f * d2 + d3;
    const float gy3 = d2 + 2.f * d3 + dR;

    float4 o;
    o.x = sqrtf(gx0 * gx0 + gy0 * gy0);
    o.y = sqrtf(gx1 * gx1 + gy1 * gy1);
    o.z = sqrtf(gx2 * gx2 + gy2 * gy2);
    o.w = sqrtf(gx3 * gx3 + gy3 * gy3);

    *reinterpret_cast<float4*>(out + img_off + (size_t)r * W + c0) = o;
}

extern "C" void kernel_launch(void* const* d_in, const int* in_sizes, int n_in,
                              void* d_out, int out_size, void* d_ws, size_t ws_size,
                              hipStream_t stream) {
    const float* x = (const float*)d_in[0];
    float* out = (float*)d_out;
    const int total_threads = B * H * G;          // 8,388,608
    const int block = 256;
    const int grid = total_threads / block;       // 32,768
    sobel_kernel<<<grid, block, 0, stream>>>(x, out);
}

// Round 5
// 46.703 us; speedup vs baseline: 2.4145x; 2.4145x over previous
//
#include <hip/hip_runtime.h>

// Sobel gradient magnitude on [B=32, 1, H=1024, W=1024] f32, zero ("SAME") padding.
// Separable: Gx = vsmooth[1,2,1] ⊗ hdiff[-1,0,1]; Gy = vdiff[-1,0,1] ⊗ hsmooth[1,2,1].
// Vertical register blocking: each thread computes R=4 output rows × 4 cols,
// loading R+2=6 row segments once (amortized 1.5 float4 loads/row vs 3).
// XCD-aware block swizzle keeps vertically-adjacent strips in the same XCD L2.

typedef float f32x4 __attribute__((ext_vector_type(4)));  // clang vector: ok for nontemporal builtins

constexpr int W = 1024;
constexpr int H = 1024;
constexpr int B = 32;
constexpr int R = 4;               // output rows per thread
constexpr int STRIPS = H / R;      // 256 strips per image
constexpr int NBLK = B * STRIPS;   // 8192 blocks (divisible by 8 XCDs)

__global__ __launch_bounds__(256) void sobel_kernel(const float* __restrict__ x,
                                                    float* __restrict__ out) {
    // Bijective XCD swizzle: HW round-robins blockIdx%8 across XCDs; remap so
    // each XCD processes a contiguous run of strips (vertical halo L2 reuse).
    const int bid = blockIdx.x;
    const int swz = (bid & 7) * (NBLK / 8) + (bid >> 3);
    const int strip = swz & (STRIPS - 1);
    const int b = swz >> 8;                 // swz / STRIPS
    const int r0 = strip * R;

    const int c0 = threadIdx.x << 2;        // 256 threads cover W=1024
    const size_t img_off = (size_t)b * H * W;
    const float* __restrict__ img = x + img_off;

    const bool has_l = (c0 > 0);
    const bool has_r = (c0 + 4 < W);

    // Load R+2 = 6 row segments (rows r0-1 .. r0+4) + left/right edge scalars
    f32x4 v[R + 2];
    float lf[R + 2], rt[R + 2];
#pragma unroll
    for (int i = 0; i < R + 2; ++i) {
        const int row = r0 - 1 + i;
        const bool valid = (row >= 0) && (row < H);   // only boundary strips predicate
        const float* rp = img + (size_t)row * W;
        v[i]  = valid ? *reinterpret_cast<const f32x4*>(rp + c0) : (f32x4)(0.f);
        lf[i] = (valid && has_l) ? rp[c0 - 1] : 0.f;
        rt[i] = (valid && has_r) ? rp[c0 + 4] : 0.f;
    }

    float* __restrict__ obase = out + img_off + (size_t)r0 * W + c0;

#pragma unroll
    for (int j = 0; j < R; ++j) {
        // Window rows: j, j+1, j+2  (image rows r0+j-1, r0+j, r0+j+1)
        const f32x4 a = v[j], m = v[j + 1], p = v[j + 2];

        // Vertical smooth t = up + 2*mid + dn; vertical diff d = dn - up
        const float tL = lf[j] + 2.f * lf[j + 1] + lf[j + 2];
        const float t0 = a.x + 2.f * m.x + p.x;
        const float t1 = a.y + 2.f * m.y + p.y;
        const float t2 = a.z + 2.f * m.z + p.z;
        const float t3 = a.w + 2.f * m.w + p.w;
        const float tR = rt[j] + 2.f * rt[j + 1] + rt[j + 2];

        const float dL = lf[j + 2] - lf[j];
        const float d0 = p.x - a.x;
        const float d1 = p.y - a.y;
        const float d2 = p.z - a.z;
        const float d3 = p.w - a.w;
        const float dR = rt[j + 2] - rt[j];

        // Horizontal: gx[k] = t[k+1] - t[k-1]; gy[k] = d[k-1] + 2*d[k] + d[k+1]
        const float gx0 = t1 - tL;
        const float gx1 = t2 - t0;
        const float gx2 = t3 - t1;
        const float gx3 = tR - t2;

        const float gy0 = dL + 2.f * d0 + d1;
        const float gy1 = d0 + 2.f * d1 + d2;
        const float gy2 = d1 + 2.f * d2 + d3;
        const float gy3 = d2 + 2.f * d3 + dR;

        f32x4 o;
        o.x = sqrtf(gx0 * gx0 + gy0 * gy0);
        o.y = sqrtf(gx1 * gx1 + gy1 * gy1);
        o.z = sqrtf(gx2 * gx2 + gy2 * gy2);
        o.w = sqrtf(gx3 * gx3 + gy3 * gy3);

        // Nontemporal store: output is never re-read; don't evict input halo from L2
        __builtin_nontemporal_store(o, reinterpret_cast<f32x4*>(obase + (size_t)j * W));
    }
}

extern "C" void kernel_launch(void* const* d_in, const int* in_sizes, int n_in,
                              void* d_out, int out_size, void* d_ws, size_t ws_size,
                              hipStream_t stream) {
    const float* x = (const float*)d_in[0];
    float* out = (float*)d_out;
    sobel_kernel<<<NBLK, 256, 0, stream>>>(x, out);
}

// Round 6
// 43.499 us; speedup vs baseline: 2.5924x; 1.0737x over previous
//
#include <hip/hip_runtime.h>

// Sobel gradient magnitude on [B=32, 1, H=1024, W=1024] f32, zero ("SAME") padding.
// Separable: Gx = vsmooth[1,2,1] ⊗ hdiff[-1,0,1]; Gy = vdiff[-1,0,1] ⊗ hsmooth[1,2,1].
// R=8 vertical register blocking: 10 row-segment loads in flight per thread (MLP),
// halo ratio 1.25x. Wave-uniform fast path for interior strips (no predication).
// XCD-aware bijective swizzle keeps vertically-adjacent strips in one XCD's L2.

typedef float f32x4 __attribute__((ext_vector_type(4)));

constexpr int W = 1024;
constexpr int H = 1024;
constexpr int B = 32;
constexpr int R = 8;               // output rows per thread
constexpr int STRIPS = H / R;      // 128 strips per image
constexpr int NBLK = B * STRIPS;   // 4096 blocks (divisible by 8 XCDs)

__global__ __launch_bounds__(256) void sobel_kernel(const float* __restrict__ x,
                                                    float* __restrict__ out) {
    // Bijective XCD swizzle: HW round-robins blockIdx%8 across XCDs; remap so
    // each XCD owns a contiguous run of strips (vertical halo reuse in its L2).
    const int bid = blockIdx.x;
    const int swz = (bid & 7) * (NBLK / 8) + (bid >> 3);
    const int strip = swz & (STRIPS - 1);
    const int b = swz >> 7;                 // swz / STRIPS (STRIPS=128)
    const int r0 = strip * R;

    const int c0 = threadIdx.x << 2;        // 256 threads cover W=1024
    const size_t img_off = (size_t)b * H * W;
    const float* __restrict__ img = x + img_off;

    const bool has_l = (c0 > 0);
    const bool has_r = (c0 + 4 < W);

    // Load R+2 = 10 row segments (rows r0-1 .. r0+8) + left/right edge scalars.
    f32x4 v[R + 2];
    float lf[R + 2], rt[R + 2];

    if (strip > 0 && strip < STRIPS - 1) {
        // Interior strip (126 of 128): all rows valid — wave-uniform fast path,
        // unconditional vector loads, maximum loads-in-flight.
        const float* rp = img + (size_t)(r0 - 1) * W;
#pragma unroll
        for (int i = 0; i < R + 2; ++i, rp += W) {
            v[i]  = *reinterpret_cast<const f32x4*>(rp + c0);
            lf[i] = has_l ? rp[c0 - 1] : 0.f;   // L1 hits (neighbor lanes' lines)
            rt[i] = has_r ? rp[c0 + 4] : 0.f;
        }
    } else {
        // Boundary strip: predicate row validity (zero padding).
#pragma unroll
        for (int i = 0; i < R + 2; ++i) {
            const int row = r0 - 1 + i;
            const bool valid = (row >= 0) && (row < H);
            const float* rp = img + (size_t)row * W;
            v[i]  = valid ? *reinterpret_cast<const f32x4*>(rp + c0) : (f32x4)(0.f);
            lf[i] = (valid && has_l) ? rp[c0 - 1] : 0.f;
            rt[i] = (valid && has_r) ? rp[c0 + 4] : 0.f;
        }
    }

    float* __restrict__ obase = out + img_off + (size_t)r0 * W + c0;

#pragma unroll
    for (int j = 0; j < R; ++j) {
        // Window rows: segments j, j+1, j+2 (image rows r0+j-1, r0+j, r0+j+1)
        const f32x4 a = v[j], m = v[j + 1], p = v[j + 2];

        // Vertical smooth t = up + 2*mid + dn; vertical diff d = dn - up
        const float tL = lf[j] + 2.f * lf[j + 1] + lf[j + 2];
        const float t0 = a.x + 2.f * m.x + p.x;
        const float t1 = a.y + 2.f * m.y + p.y;
        const float t2 = a.z + 2.f * m.z + p.z;
        const float t3 = a.w + 2.f * m.w + p.w;
        const float tR = rt[j] + 2.f * rt[j + 1] + rt[j + 2];

        const float dL = lf[j + 2] - lf[j];
        const float d0 = p.x - a.x;
        const float d1 = p.y - a.y;
        const float d2 = p.z - a.z;
        const float d3 = p.w - a.w;
        const float dR = rt[j + 2] - rt[j];

        // Horizontal: gx[k] = t[k+1] - t[k-1]; gy[k] = d[k-1] + 2*d[k] + d[k+1]
        const float gx0 = t1 - tL;
        const float gx1 = t2 - t0;
        const float gx2 = t3 - t1;
        const float gx3 = tR - t2;

        const float gy0 = dL + 2.f * d0 + d1;
        const float gy1 = d0 + 2.f * d1 + d2;
        const float gy2 = d1 + 2.f * d2 + d3;
        const float gy3 = d2 + 2.f * d3 + dR;

        f32x4 o;
        // v_sqrt_f32 (~1 ulp) — absolute threshold is 0.42, exact fixup not needed
        o.x = __builtin_amdgcn_sqrtf(gx0 * gx0 + gy0 * gy0);
        o.y = __builtin_amdgcn_sqrtf(gx1 * gx1 + gy1 * gy1);
        o.z = __builtin_amdgcn_sqrtf(gx2 * gx2 + gy2 * gy2);
        o.w = __builtin_amdgcn_sqrtf(gx3 * gx3 + gy3 * gy3);

        // Nontemporal store: output never re-read; don't evict input halo from L2
        __builtin_nontemporal_store(o, reinterpret_cast<f32x4*>(obase + (size_t)j * W));
    }
}

extern "C" void kernel_launch(void* const* d_in, const int* in_sizes, int n_in,
                              void* d_out, int out_size, void* d_ws, size_t ws_size,
                              hipStream_t stream) {
    const float* x = (const float*)d_in[0];
    float* out = (float*)d_out;
    sobel_kernel<<<NBLK, 256, 0, stream>>>(x, out);
}